// Round 12
// baseline (157.484 us; speedup 1.0000x reference)
//
#include <hip/hip_runtime.h>
#include <hip/hip_bf16.h>

#define NNODES 4096
#define NEDGES 131072
#define D_IN   768
#define D_H    256
#define NHEAD  4
#define D_HEAD 64
#define D_OUT  128
#define DEGCAP 192

typedef __attribute__((ext_vector_type(4))) float f32x4;
typedef __attribute__((ext_vector_type(8))) short bf16x8;
typedef __attribute__((ext_vector_type(8))) unsigned short u16x8;

static __device__ __forceinline__ unsigned short f2bf(float f) {
    __hip_bfloat16 h = __float2bfloat16(f);
    return *reinterpret_cast<unsigned short*>(&h);
}
static __device__ __forceinline__ float bf2f(unsigned short u) {
    return __uint_as_float((unsigned)u << 16);
}

// ---------------- workspace layout (bytes) ----------------
#define OFF_H0     (0u)                          // 4MB f32
#define OFF_H1     (4u<<20)                      // 4MB f32
#define OFF_HH     (8u<<20)                      // 2MB bf16
#define OFF_SPART  (10u<<20)                     // 128*256*4 = 131072
#define OFF_SSRC   (OFF_SPART + 131072u)         // 65536
#define OFF_SDST   (OFF_SSRC + 65536u)           // 65536
#define OFF_S      (OFF_SDST + 65536u)           // 1024
#define OFF_CTR    (OFF_S + 1024u)               // 256
#define OFF_WINT   (OFF_CTR + 256u)              // 393216
#define OFF_WGT    (OFF_WINT + 393216u)          // 262144
#define OFF_WOUTT  (OFF_WGT + 262144u)           // 65536
#define OFF_BM     (OFF_WOUTT + 65536u)          // 2MB

struct GemmShared {
    unsigned short As[32][72];
    unsigned short Bs[64][72];
    float sredS[4][32];
    float sredD[4][32];
};

// ---------------- init: zero bitmap + counters, tiled weight convert ----------------
// 512 blocks. Tiles: Win 24x8=192 (bid 0..191), Wg 8 mats x 16 = 128 (192..319),
// Wout 8x4=32 (320..351). LDS 32x33 transpose tiles (coalesced both sides).
__global__ __launch_bounds__(256) void k_init(
    const float* __restrict__ Win, const float* __restrict__ Wg,
    const float* __restrict__ Wout,
    unsigned short* __restrict__ WinT, unsigned short* __restrict__ WgT,
    unsigned short* __restrict__ WoutT,
    uint4* __restrict__ bm4, int* __restrict__ ctr)
{
    __shared__ float tile[32][33];
    const int tid = threadIdx.x, bid = blockIdx.x;
    bm4[bid*256 + tid] = make_uint4(0u,0u,0u,0u);
    if (bid == 0 && tid < 8) ctr[tid] = 0;

    if (bid < 352) {
        const float* src; unsigned short* dst; int R, Cc, tr, tc;
        if (bid < 192)      { src = Win;  dst = WinT;  R = 768; Cc = 256; tr = bid >> 3; tc = bid & 7; }
        else if (bid < 320) { int t = bid - 192; int m = t >> 4, s = t & 15;
                              src = Wg + (size_t)m*16384; dst = WgT + (size_t)m*16384;
                              R = 256; Cc = 64; tr = s >> 1; tc = s & 1; }
        else                { int t = bid - 320; src = Wout; dst = WoutT;
                              R = 256; Cc = 128; tr = t >> 2; tc = t & 3; }
        int ci = tid & 31, rq = tid >> 5;
        #pragma unroll
        for (int rr = rq; rr < 32; rr += 8)
            tile[rr][ci] = src[(size_t)(tr*32+rr)*Cc + tc*32 + ci];
        __syncthreads();
        int ri = tid & 31, cq = tid >> 5;
        #pragma unroll
        for (int cc = cq; cc < 32; cc += 8)
            dst[(size_t)(tc*32+cc)*R + tr*32 + ri] = f2bf(tile[ri][cc]);
    }
}

// ---------------- MFMA GEMM (32x64 tile, BK=64, 4 waves) ----------------
// round-9-proven body. Optional extras:
//  a_l != null : scores + Spart epilogue, Cb out, then last-done-block
//                reduces Spart (order b=0..127, bit-identical to colsum2) -> S.
//  ei  != null : adjacency-bitmap build appended (512 blocks x 256 thr = NEDGES).
__global__ __launch_bounds__(256) void k_gemm(
    const float* __restrict__ A, const unsigned short* __restrict__ BT,
    const float* __restrict__ bias, float* __restrict__ Cf,
    unsigned short* __restrict__ Cb, int N, int K, int relu,
    const float* __restrict__ a_l, float* __restrict__ ssrc,
    float* __restrict__ sdst, float* __restrict__ Spart,
    int* __restrict__ ctr, float* __restrict__ S,
    const int* __restrict__ ei, unsigned* __restrict__ bm)
{
    __shared__ GemmShared sm;
    const int bx = blockIdx.x, by = blockIdx.y;
    const int tid = threadIdx.x;
    const int wc = tid >> 6;
    const int lane = tid & 63;
    const int g = lane >> 4, c = lane & 15;
    const int ar = tid >> 3, ak = (tid & 7) * 8;
    const int bc = tid >> 2, bk = (tid & 3) * 16;
    f32x4 acc0 = {0.f,0.f,0.f,0.f}, acc1 = {0.f,0.f,0.f,0.f};
    const float* Arow = A + (size_t)(by*32 + ar)*K;
    const unsigned short* Brow = BT + (size_t)(bx*64 + bc)*K;

    for (int k0 = 0; k0 < K; k0 += 64) {
        float4 av0 = *(const float4*)&Arow[k0 + ak];
        float4 av1 = *(const float4*)&Arow[k0 + ak + 4];
        u16x8 bv0 = *(const u16x8*)&Brow[k0 + bk];
        u16x8 bv1 = *(const u16x8*)&Brow[k0 + bk + 8];
        ushort4 aw0, aw1;
        aw0.x = f2bf(av0.x); aw0.y = f2bf(av0.y); aw0.z = f2bf(av0.z); aw0.w = f2bf(av0.w);
        aw1.x = f2bf(av1.x); aw1.y = f2bf(av1.y); aw1.z = f2bf(av1.z); aw1.w = f2bf(av1.w);
        *(ushort4*)&sm.As[ar][ak]     = aw0;
        *(ushort4*)&sm.As[ar][ak + 4] = aw1;
        *(u16x8*)&sm.Bs[bc][bk]     = bv0;
        *(u16x8*)&sm.Bs[bc][bk + 8] = bv1;
        __syncthreads();
        bf16x8 b0  = *(bf16x8*)&sm.Bs[wc*16 + c][g*8];
        bf16x8 b1  = *(bf16x8*)&sm.Bs[wc*16 + c][32 + g*8];
        bf16x8 a00 = *(bf16x8*)&sm.As[c][g*8];
        bf16x8 a01 = *(bf16x8*)&sm.As[c][32 + g*8];
        bf16x8 a10 = *(bf16x8*)&sm.As[16 + c][g*8];
        bf16x8 a11 = *(bf16x8*)&sm.As[16 + c][32 + g*8];
        acc0 = __builtin_amdgcn_mfma_f32_16x16x32_bf16(a00, b0, acc0, 0, 0, 0);
        acc0 = __builtin_amdgcn_mfma_f32_16x16x32_bf16(a01, b1, acc0, 0, 0, 0);
        acc1 = __builtin_amdgcn_mfma_f32_16x16x32_bf16(a10, b0, acc1, 0, 0, 0);
        acc1 = __builtin_amdgcn_mfma_f32_16x16x32_bf16(a11, b1, acc1, 0, 0, 0);
        __syncthreads();
    }

    const int col = bx*64 + wc*16 + c;
    float bb = bias ? bias[col] : 0.f;
    #pragma unroll
    for (int t = 0; t < 2; ++t) {
        f32x4 av = t ? acc1 : acc0;
        #pragma unroll
        for (int i = 0; i < 4; ++i) {
            int r = by*32 + t*16 + g*4 + i;
            float v = av[i] + bb;
            if (relu) v = fmaxf(v, 0.f);
            if (Cb) Cb[(size_t)r*N + col] = f2bf(v);
            else    Cf[(size_t)r*N + col] = v;
        }
    }

    if (a_l) {
        int h = bx;
        float as = a_l[h*128 + wc*16 + c];
        float ad = a_l[h*128 + 64 + wc*16 + c];
        float ps[8], pd[8], cs = 0.f;
        #pragma unroll
        for (int t = 0; t < 2; ++t) {
            f32x4 av = t ? acc1 : acc0;
            #pragma unroll
            for (int i = 0; i < 4; ++i) {
                ps[t*4+i] = av[i] * as;
                pd[t*4+i] = av[i] * ad;
                cs += av[i];
            }
        }
        #pragma unroll
        for (int off = 1; off < 16; off <<= 1) {
            #pragma unroll
            for (int j = 0; j < 8; ++j) {
                ps[j] += __shfl_xor(ps[j], off);
                pd[j] += __shfl_xor(pd[j], off);
            }
        }
        if (c == 0) {
            #pragma unroll
            for (int t = 0; t < 2; ++t)
                #pragma unroll
                for (int i = 0; i < 4; ++i) {
                    sm.sredS[wc][t*16 + g*4 + i] = ps[t*4+i];
                    sm.sredD[wc][t*16 + g*4 + i] = pd[t*4+i];
                }
        }
        cs += __shfl_xor(cs, 16);
        cs += __shfl_xor(cs, 32);
        if (g == 0)
            Spart[by*256 + col] = cs;
        __syncthreads();
        if (tid < 32) {
            float s1 = sm.sredS[0][tid] + sm.sredS[1][tid] + sm.sredS[2][tid] + sm.sredS[3][tid];
            float s2 = sm.sredD[0][tid] + sm.sredD[1][tid] + sm.sredD[2][tid] + sm.sredD[3][tid];
            int r = by*32 + tid;
            ssrc[r*4 + h] = s1;
            sdst[r*4 + h] = s2;
        }
        // ---- last-done block reduces Spart -> S (replaces colsum2 dispatch) ----
        __shared__ int lastf;
        __syncthreads();
        __threadfence();                         // publish this block's Spart
        if (tid == 0) {
            int old = atomicAdd(ctr, 1);         // int atomic: value-deterministic
            lastf = (old == (int)(gridDim.x*gridDim.y) - 1) ? 1 : 0;
        }
        __syncthreads();
        if (lastf) {
            __threadfence();                     // acquire all blocks' Spart
            float s = 0.f;
            for (int b = 0; b < 128; ++b) s += Spart[b*256 + tid];  // colsum2 order
            S[tid] = s;
        }
    }

    if (ei) {
        // adjacency bitmap build: 512 blocks x 256 threads == NEDGES
        __shared__ int flag;
        int bid = blockIdx.y*gridDim.x + blockIdx.x;
        if (tid < 64) {
            int v = ei[2*tid + 1];
            unsigned long long ball = __ballot(v == 0);
            if (tid == 0) flag = (ball == ~0ull) ? 1 : 0;
        }
        __syncthreads();
        int is64 = flag;
        int k = bid*256 + tid;
        int r = is64 ? ei[2*k]            : ei[k];
        int cc = is64 ? ei[2*NEDGES + 2*k] : ei[NEDGES + k];
        r &= (NNODES-1); cc &= (NNODES-1);
        atomicOr(&bm[(size_t)r*128 + (cc>>5)], 1u << (cc & 31));
    }
}

// ---------------- aggregation (round-9 internals: 4096 blocks x 1 node) ----------------
// Exact dense-softmax identity:
//   M = max(0, max_e e); base = exp(-M)
//   Z = sum_edges(exp(e-M)-base) + N*base
//   hp = [ sum_edges (exp(e-M)-base)*hh[m] + base*S ] / Z
__global__ __launch_bounds__(256) void k_agg(
    const unsigned* __restrict__ bm, const float* __restrict__ ssrc,
    const float* __restrict__ sdst, const unsigned short* __restrict__ hh,
    const float* __restrict__ S, float* __restrict__ hout)
{
    __shared__ int   csr[DEGCAP];
    __shared__ float wl[4*DEGCAP];
    __shared__ int   cnt_sh;
    const int n = blockIdx.x;
    const int tid = threadIdx.x;
    const int h = tid >> 6, o = tid & 63;
    const unsigned* brow = bm + (size_t)n*128;

    if (tid < 64) {
        unsigned wA = brow[2*tid], wB = brow[2*tid + 1];
        int cpc = __popc(wA) + __popc(wB);
        int pre = cpc;
        #pragma unroll
        for (int off = 1; off < 64; off <<= 1) {
            int v = __shfl_up(pre, off);
            if (tid >= off) pre += v;
        }
        int excl = pre - cpc;
        int total = __shfl(pre, 63);
        if (total <= DEGCAP) {
            int pos = excl, base = tid*64;
            unsigned w = wA;
            while (w) { int b = __builtin_ctz(w); csr[pos++] = base + b; w &= w-1; }
            w = wB; base += 32;
            while (w) { int b = __builtin_ctz(w); csr[pos++] = base + b; w &= w-1; }
        }
        if (tid == 0) cnt_sh = total;
    }
    __syncthreads();
    int cnt = cnt_sh;
    float ss = ssrc[n*4 + h];

    if (cnt <= DEGCAP) {
        float mx = 0.f;
        for (int i = o; i < cnt; i += 64) {
            int m = csr[i];
            float e = ss + sdst[m*4 + h];
            e = (e >= 0.f) ? e : 0.2f*e;
            mx = fmaxf(mx, e);
        }
        #pragma unroll
        for (int off = 32; off; off >>= 1) mx = fmaxf(mx, __shfl_xor(mx, off));
        float M = mx;
        float base = expf(-M);

        float zp = 0.f;
        for (int i = o; i < cnt; i += 64) {
            int m = csr[i];
            float e = ss + sdst[m*4 + h];
            e = (e >= 0.f) ? e : 0.2f*e;
            float w = expf(e - M) - base;
            wl[h*DEGCAP + i] = w;
            zp += w;
        }
        #pragma unroll
        for (int off = 32; off; off >>= 1) zp += __shfl_xor(zp, off);

        float acc = 0.f;
        int i = 0;
        for (; i + 4 <= cnt; i += 4) {
            int m0 = csr[i],   m1 = csr[i+1];
            int m2 = csr[i+2], m3 = csr[i+3];
            float w0 = wl[h*DEGCAP+i],   w1 = wl[h*DEGCAP+i+1];
            float w2 = wl[h*DEGCAP+i+2], w3 = wl[h*DEGCAP+i+3];
            float v0 = bf2f(hh[(size_t)m0*256 + h*64 + o]);
            float v1 = bf2f(hh[(size_t)m1*256 + h*64 + o]);
            float v2 = bf2f(hh[(size_t)m2*256 + h*64 + o]);
            float v3 = bf2f(hh[(size_t)m3*256 + h*64 + o]);
            acc += w0*v0; acc += w1*v1; acc += w2*v2; acc += w3*v3;
        }
        for (; i < cnt; ++i)
            acc += wl[h*DEGCAP+i] * bf2f(hh[(size_t)csr[i]*256 + h*64 + o]);

        float Z  = zp + (float)NNODES * base;
        float hp = (acc + base * S[tid]) / Z;
        hout[(size_t)n*256 + tid] = fmaxf(hp, 0.f);
    } else {
        float mx = 0.f;
        for (int m = o; m < NNODES; m += 64) {
            if ((brow[m>>5] >> (m & 31)) & 1u) {
                float e = ss + sdst[m*4 + h];
                e = (e >= 0.f) ? e : 0.2f*e;
                mx = fmaxf(mx, e);
            }
        }
        #pragma unroll
        for (int off = 32; off; off >>= 1) mx = fmaxf(mx, __shfl_xor(mx, off));
        float M = mx;
        float base = expf(-M);
        float zp = 0.f, acc = 0.f;
        for (int m = 0; m < NNODES; ++m) {
            if ((brow[m>>5] >> (m & 31)) & 1u) {
                float e = ss + sdst[m*4 + h];
                e = (e >= 0.f) ? e : 0.2f*e;
                float w = expf(e - M) - base;
                zp += w;
                acc += w * bf2f(hh[(size_t)m*256 + h*64 + o]);
            }
        }
        float Z  = zp + (float)NNODES * base;
        float hp = (acc + base * S[tid]) / Z;
        hout[(size_t)n*256 + tid] = fmaxf(hp, 0.f);
    }
}

// ---------------- host ----------------
static int find_size(const int* sz, int n, int want, int fallback)
{
    for (int i = 0; i < n; ++i) if (sz[i] == want) return i;
    return fallback;
}

extern "C" void kernel_launch(void* const* d_in, const int* in_sizes, int n_in,
                              void* d_out, int out_size, void* d_ws, size_t ws_size,
                              hipStream_t stream)
{
    int ix   = find_size(in_sizes, n_in, NNODES*D_IN, 0);
    int ie   = find_size(in_sizes, n_in, 2*NEDGES, 1);
    int iwin = find_size(in_sizes, n_in, D_IN*D_H, 2);
    int ibin = find_size(in_sizes, n_in, D_H, 3);
    int iwg  = find_size(in_sizes, n_in, 2*NHEAD*D_H*D_HEAD, 4);
    int ia   = find_size(in_sizes, n_in, 2*NHEAD*2*D_HEAD, 5);
    int iwo  = find_size(in_sizes, n_in, D_H*D_OUT, 6);
    int ibo  = find_size(in_sizes, n_in, D_OUT, 7);

    const float* x    = (const float*)d_in[ix];
    const int*   ei   = (const int*)d_in[ie];
    const float* Win  = (const float*)d_in[iwin];
    const float* bin_ = (const float*)d_in[ibin];
    const float* Wg   = (const float*)d_in[iwg];
    const float* a    = (const float*)d_in[ia];
    const float* Wout = (const float*)d_in[iwo];
    const float* bout = (const float*)d_in[ibo];
    float* out = (float*)d_out;

    char* ws = (char*)d_ws;
    float*          h0    = (float*)(ws + OFF_H0);
    float*          h1    = (float*)(ws + OFF_H1);
    unsigned short* hh    = (unsigned short*)(ws + OFF_HH);
    float*          Spart = (float*)(ws + OFF_SPART);
    float*          ssrc  = (float*)(ws + OFF_SSRC);
    float*          sdst  = (float*)(ws + OFF_SDST);
    float*          S     = (float*)(ws + OFF_S);
    int*            ctr   = (int*)(ws + OFF_CTR);
    unsigned short* WinT  = (unsigned short*)(ws + OFF_WINT);
    unsigned short* WgT   = (unsigned short*)(ws + OFF_WGT);
    unsigned short* WoutT = (unsigned short*)(ws + OFF_WOUTT);
    unsigned*       bm    = (unsigned*)(ws + OFF_BM);

    // d1: zero bitmap+counters, convert weights (tiled)
    k_init<<<512, 256, 0, stream>>>(Win, Wg, Wout, WinT, WgT, WoutT, (uint4*)bm, ctr);

    // d2: h0 = relu(x @ Win + bin)  + adjacency bitmap build (fused tail)
    {
        dim3 g(D_H/64, NNODES/32);
        k_gemm<<<g, 256, 0, stream>>>(x, WinT, bin_, h0, nullptr, D_H, D_IN, 1,
                                      nullptr, nullptr, nullptr, nullptr,
                                      nullptr, nullptr, ei, bm);
    }

    float* hin = h0;
    float* hcur = h1;
    for (int l = 0; l < 2; ++l) {
        // d3/d5: hh = hin @ Wg[l]  (+ scores, Spart, last-block S reduce)
        dim3 g2(D_H/64, NNODES/32);
        k_gemm<<<g2, 256, 0, stream>>>(hin, WgT + (size_t)l*NHEAD*D_HEAD*D_H,
                                       nullptr, nullptr, hh, D_H, D_H, 0,
                                       a + (size_t)l*NHEAD*128, ssrc, sdst, Spart,
                                       ctr + l, S, nullptr, nullptr);
        // d4/d6: aggregate
        k_agg<<<NNODES, 256, 0, stream>>>(bm, ssrc, sdst, hh, S, hcur);
        float* t = hin; hin = hcur; hcur = t;
    }

    // d7: out = hin @ Wout + bout
    {
        dim3 g(D_OUT/64, NNODES/32);
        k_gemm<<<g, 256, 0, stream>>>(hin, WoutT, bout, out, nullptr, D_OUT, D_H, 0,
                                      nullptr, nullptr, nullptr, nullptr,
                                      nullptr, nullptr, nullptr, nullptr);
    }
}

// Round 13
// 86.800 us; speedup vs baseline: 1.8143x; 1.8143x over previous
//
#include <hip/hip_runtime.h>
#include <hip/hip_bf16.h>

#define NNODES 4096
#define NEDGES 131072
#define D_IN   768
#define D_H    256
#define NHEAD  4
#define D_HEAD 64
#define D_OUT  128
#define DEGCAP 192

typedef __attribute__((ext_vector_type(4))) float f32x4;
typedef __attribute__((ext_vector_type(8))) short bf16x8;
typedef __attribute__((ext_vector_type(8))) unsigned short u16x8;

static __device__ __forceinline__ unsigned short f2bf(float f) {
    __hip_bfloat16 h = __float2bfloat16(f);
    return *reinterpret_cast<unsigned short*>(&h);
}
static __device__ __forceinline__ float bf2f(unsigned short u) {
    return __uint_as_float((unsigned)u << 16);
}

// ---------------- workspace layout (bytes) ----------------
#define OFF_H0     (0u)                          // 4MB f32
#define OFF_H1     (4u<<20)                      // 4MB f32
#define OFF_HH     (8u<<20)                      // 2MB bf16
#define OFF_SPART  (10u<<20)                     // 128*256*4 = 131072
#define OFF_SSRC   (OFF_SPART + 131072u)         // 65536
#define OFF_SDST   (OFF_SSRC + 65536u)           // 65536
#define OFF_S      (OFF_SDST + 65536u)           // 1024
#define OFF_WINT   (OFF_S + 1024u)               // 393216
#define OFF_WGT    (OFF_WINT + 393216u)          // 262144
#define OFF_WOUTT  (OFF_WGT + 262144u)           // 65536
#define OFF_BM     (OFF_WOUTT + 65536u)          // 2MB

// ---------------- init: zero bitmap + tiled weight convert (fused, coalesced) ----------------
// 512 blocks. Tiles: Win 24x8=192 (bid 0..191), Wg 8 mats x 16 (192..319),
// Wout 8x4=32 (320..351). LDS 32x33 transpose tiles; bm zero via uint4 stores.
__global__ __launch_bounds__(256) void k_init(
    const float* __restrict__ Win, const float* __restrict__ Wg,
    const float* __restrict__ Wout,
    unsigned short* __restrict__ WinT, unsigned short* __restrict__ WgT,
    unsigned short* __restrict__ WoutT, uint4* __restrict__ bm4)
{
    __shared__ float tile[32][33];
    const int tid = threadIdx.x, bid = blockIdx.x;
    bm4[bid*256 + tid] = make_uint4(0u,0u,0u,0u);

    if (bid < 352) {
        const float* src; unsigned short* dst; int R, Cc, tr, tc;
        if (bid < 192)      { src = Win;  dst = WinT;  R = 768; Cc = 256; tr = bid >> 3; tc = bid & 7; }
        else if (bid < 320) { int t = bid - 192; int m = t >> 4, s = t & 15;
                              src = Wg + (size_t)m*16384; dst = WgT + (size_t)m*16384;
                              R = 256; Cc = 64; tr = s >> 1; tc = s & 1; }
        else                { int t = bid - 320; src = Wout; dst = WoutT;
                              R = 256; Cc = 128; tr = t >> 2; tc = t & 3; }
        int ci = tid & 31, rq = tid >> 5;
        #pragma unroll
        for (int rr = rq; rr < 32; rr += 8)
            tile[rr][ci] = src[(size_t)(tr*32+rr)*Cc + tc*32 + ci];
        __syncthreads();
        int ri = tid & 31, cq = tid >> 5;
        #pragma unroll
        for (int cc = cq; cc < 32; cc += 8)
            dst[(size_t)(tc*32+cc)*R + tr*32 + ri] = f2bf(tile[ri][cc]);
    }
}

// ---------------- adjacency bitmap (fused dtype autodetect; idempotent) ----------------
__global__ void edge_bitmap(const int* __restrict__ ei, unsigned* __restrict__ bm)
{
    __shared__ int is64_sh;
    int tid = threadIdx.x;
    if (tid < 64) {
        int v = ei[2*tid + 1];
        unsigned long long ball = __ballot(v == 0);
        if (tid == 0) is64_sh = (ball == ~0ull) ? 1 : 0;
    }
    __syncthreads();
    int is64 = is64_sh;
    int k = blockIdx.x*256 + tid;
    if (k >= NEDGES) return;
    int r = is64 ? ei[2*k]            : ei[k];
    int c = is64 ? ei[2*NEDGES + 2*k] : ei[NEDGES + k];
    r &= (NNODES-1); c &= (NNODES-1);
    atomicOr(&bm[(size_t)r*128 + (c>>5)], 1u << (c & 31));
}

// ---------------- MFMA GEMM: C = act(A@B + bias)  [round-8-proven body] ----------------
// A: MxK f32 (bf16-converted during staging). BT: NxK bf16 (pre-transposed).
// 32x64 tile, BK=64, 256 thr = 4 waves (wave = 16-col strip), 4 MFMA/wave/iter.
// a_l != null (hh GEMM): epilogue computes ssrc/sdst + Spart col sums, C->bf16.
__global__ __launch_bounds__(256) void gemm_mfma(
    const float* __restrict__ A, const unsigned short* __restrict__ BT,
    const float* __restrict__ bias, float* __restrict__ Cf,
    unsigned short* __restrict__ Cb,
    int M, int N, int K, int relu,
    const float* __restrict__ a_l, float* __restrict__ ssrc,
    float* __restrict__ sdst, float* __restrict__ Spart)
{
    __shared__ unsigned short As[32][72];   // [row][k] bf16, 144B stride (2-way banks: free)
    __shared__ unsigned short Bs[64][72];   // [col][k] bf16
    __shared__ float sredS[4][32], sredD[4][32];
    const int tid = threadIdx.x;
    const int bx = blockIdx.x, by = blockIdx.y;
    const int wc = tid >> 6;                 // wave id = column strip
    const int lane = tid & 63;
    const int g = lane >> 4, c = lane & 15;
    const int ar = tid >> 3, ak = (tid & 7) * 8;   // A stage: 32r x (8thr x 8 f32)
    const int bc = tid >> 2, bk = (tid & 3) * 16;  // B stage: 64c x (4thr x 16 u16)
    f32x4 acc0 = {0.f,0.f,0.f,0.f}, acc1 = {0.f,0.f,0.f,0.f};
    const float* Arow = A + (size_t)(by*32 + ar)*K;
    const unsigned short* Brow = BT + (size_t)(bx*64 + bc)*K;

    for (int k0 = 0; k0 < K; k0 += 64) {
        float4 av0 = *(const float4*)&Arow[k0 + ak];
        float4 av1 = *(const float4*)&Arow[k0 + ak + 4];
        u16x8 bv0 = *(const u16x8*)&Brow[k0 + bk];
        u16x8 bv1 = *(const u16x8*)&Brow[k0 + bk + 8];
        ushort4 aw0, aw1;
        aw0.x = f2bf(av0.x); aw0.y = f2bf(av0.y); aw0.z = f2bf(av0.z); aw0.w = f2bf(av0.w);
        aw1.x = f2bf(av1.x); aw1.y = f2bf(av1.y); aw1.z = f2bf(av1.z); aw1.w = f2bf(av1.w);
        *(ushort4*)&As[ar][ak]     = aw0;
        *(ushort4*)&As[ar][ak + 4] = aw1;
        *(u16x8*)&Bs[bc][bk]     = bv0;
        *(u16x8*)&Bs[bc][bk + 8] = bv1;
        __syncthreads();
        bf16x8 b0  = *(bf16x8*)&Bs[wc*16 + c][g*8];
        bf16x8 b1  = *(bf16x8*)&Bs[wc*16 + c][32 + g*8];
        bf16x8 a00 = *(bf16x8*)&As[c][g*8];
        bf16x8 a01 = *(bf16x8*)&As[c][32 + g*8];
        bf16x8 a10 = *(bf16x8*)&As[16 + c][g*8];
        bf16x8 a11 = *(bf16x8*)&As[16 + c][32 + g*8];
        acc0 = __builtin_amdgcn_mfma_f32_16x16x32_bf16(a00, b0, acc0, 0, 0, 0);
        acc0 = __builtin_amdgcn_mfma_f32_16x16x32_bf16(a01, b1, acc0, 0, 0, 0);
        acc1 = __builtin_amdgcn_mfma_f32_16x16x32_bf16(a10, b0, acc1, 0, 0, 0);
        acc1 = __builtin_amdgcn_mfma_f32_16x16x32_bf16(a11, b1, acc1, 0, 0, 0);
        __syncthreads();
    }

    const int col = bx*64 + wc*16 + c;
    float bb = bias ? bias[col] : 0.f;
    #pragma unroll
    for (int t = 0; t < 2; ++t) {
        f32x4 av = t ? acc1 : acc0;
        #pragma unroll
        for (int i = 0; i < 4; ++i) {
            int r = by*32 + t*16 + g*4 + i;
            float v = av[i] + bb;
            if (relu) v = fmaxf(v, 0.f);
            if (Cb) Cb[(size_t)r*N + col] = f2bf(v);
            else    Cf[(size_t)r*N + col] = v;
        }
    }

    if (a_l) {
        int h = bx;
        float as = a_l[h*128 + wc*16 + c];
        float ad = a_l[h*128 + 64 + wc*16 + c];
        float ps[8], pd[8], cs = 0.f;
        #pragma unroll
        for (int t = 0; t < 2; ++t) {
            f32x4 av = t ? acc1 : acc0;
            #pragma unroll
            for (int i = 0; i < 4; ++i) {
                ps[t*4+i] = av[i] * as;
                pd[t*4+i] = av[i] * ad;
                cs += av[i];
            }
        }
        #pragma unroll
        for (int off = 1; off < 16; off <<= 1) {
            #pragma unroll
            for (int j = 0; j < 8; ++j) {
                ps[j] += __shfl_xor(ps[j], off);
                pd[j] += __shfl_xor(pd[j], off);
            }
        }
        if (c == 0) {
            #pragma unroll
            for (int t = 0; t < 2; ++t)
                #pragma unroll
                for (int i = 0; i < 4; ++i) {
                    sredS[wc][t*16 + g*4 + i] = ps[t*4+i];
                    sredD[wc][t*16 + g*4 + i] = pd[t*4+i];
                }
        }
        cs += __shfl_xor(cs, 16);
        cs += __shfl_xor(cs, 32);
        if (g == 0)
            Spart[by*256 + h*64 + wc*16 + c] = cs;
        __syncthreads();
        if (tid < 32) {
            float s1 = sredS[0][tid] + sredS[1][tid] + sredS[2][tid] + sredS[3][tid];
            float s2 = sredD[0][tid] + sredD[1][tid] + sredD[2][tid] + sredD[3][tid];
            int r = by*32 + tid;
            ssrc[r*4 + h] = s1;
            sdst[r*4 + h] = s2;
        }
    }
}

// ---------------- colsum stage 2: S[c] = sum_by Spart[by][c] ----------------
__global__ void colsum2(const float* __restrict__ Spart, float* __restrict__ S)
{
    int j = threadIdx.x;
    float s = 0.f;
    for (int b = 0; b < 128; ++b) s += Spart[b*256 + j];
    S[j] = s;                     // deterministic
}

// ---------------- per-node aggregation + dense-softmax + relu ----------------
// Neighbor list built in-kernel from the bitmap row. Exact dense-softmax identity:
//   M = max(0, max_e e); base = exp(-M)
//   Z = sum_edges(exp(e-M)-base) + N*base
//   hp = [ sum_edges (exp(e-M)-base)*hh[m] + base*S ] / Z
__global__ __launch_bounds__(256) void aggregate_kernel(
    const unsigned* __restrict__ bm,
    const float* __restrict__ ssrc, const float* __restrict__ sdst,
    const unsigned short* __restrict__ hh, const float* __restrict__ S,
    float* __restrict__ hout)
{
    __shared__ int   csr_lds[DEGCAP];
    __shared__ float w_lds[4*DEGCAP];
    __shared__ int   cnt_sh;
    int n = blockIdx.x;
    int tid = threadIdx.x;
    int h = tid >> 6, o = tid & 63;
    const unsigned* brow = bm + (size_t)n*128;

    if (tid < 64) {
        unsigned wA = brow[2*tid], wB = brow[2*tid + 1];
        int cpc = __popc(wA) + __popc(wB);
        int pre = cpc;
        #pragma unroll
        for (int off = 1; off < 64; off <<= 1) {
            int v = __shfl_up(pre, off);
            if (tid >= off) pre += v;
        }
        int excl = pre - cpc;
        int total = __shfl(pre, 63);
        if (total <= DEGCAP) {
            int pos = excl, base = tid*64;
            unsigned w = wA;
            while (w) { int b = __builtin_ctz(w); csr_lds[pos++] = base + b; w &= w-1; }
            w = wB; base += 32;
            while (w) { int b = __builtin_ctz(w); csr_lds[pos++] = base + b; w &= w-1; }
        }
        if (tid == 0) cnt_sh = total;
    }
    __syncthreads();
    int cnt = cnt_sh;
    float ss = ssrc[n*4 + h];

    if (cnt <= DEGCAP) {
        float mx = 0.f;
        for (int i = o; i < cnt; i += 64) {
            int m = csr_lds[i];
            float e = ss + sdst[m*4 + h];
            e = (e >= 0.f) ? e : 0.2f*e;
            mx = fmaxf(mx, e);
        }
        #pragma unroll
        for (int off = 32; off; off >>= 1) mx = fmaxf(mx, __shfl_xor(mx, off));
        float M = mx;
        float base = expf(-M);

        float zp = 0.f;
        for (int i = o; i < cnt; i += 64) {
            int m = csr_lds[i];
            float e = ss + sdst[m*4 + h];
            e = (e >= 0.f) ? e : 0.2f*e;
            float w = expf(e - M) - base;
            w_lds[h*DEGCAP + i] = w;
            zp += w;
        }
        #pragma unroll
        for (int off = 32; off; off >>= 1) zp += __shfl_xor(zp, off);

        // accumulate: 8 independent gathers in flight (same sequential FP order)
        float acc = 0.f;
        int i = 0;
        for (; i + 8 <= cnt; i += 8) {
            int   mm[8]; float wq[8]; float vq[8];
            #pragma unroll
            for (int j = 0; j < 8; ++j) {
                mm[j] = csr_lds[i+j];
                wq[j] = w_lds[h*DEGCAP + i + j];
            }
            #pragma unroll
            for (int j = 0; j < 8; ++j)
                vq[j] = bf2f(hh[(size_t)mm[j]*256 + h*64 + o]);
            #pragma unroll
            for (int j = 0; j < 8; ++j)
                acc += wq[j] * vq[j];
        }
        for (; i < cnt; ++i)
            acc += w_lds[h*DEGCAP+i] * bf2f(hh[(size_t)csr_lds[i]*256 + h*64 + o]);

        float Z  = zp + (float)NNODES * base;
        float hp = (acc + base * S[h*64 + o]) / Z;
        hout[(size_t)n*256 + h*64 + o] = fmaxf(hp, 0.f);
    } else {
        float mx = 0.f;
        for (int m = o; m < NNODES; m += 64) {
            if ((brow[m>>5] >> (m & 31)) & 1u) {
                float e = ss + sdst[m*4 + h];
                e = (e >= 0.f) ? e : 0.2f*e;
                mx = fmaxf(mx, e);
            }
        }
        #pragma unroll
        for (int off = 32; off; off >>= 1) mx = fmaxf(mx, __shfl_xor(mx, off));
        float M = mx;
        float base = expf(-M);
        float zp = 0.f, acc = 0.f;
        for (int m = 0; m < NNODES; ++m) {
            if ((brow[m>>5] >> (m & 31)) & 1u) {
                float e = ss + sdst[m*4 + h];
                e = (e >= 0.f) ? e : 0.2f*e;
                float w = expf(e - M) - base;
                zp += w;
                acc += w * bf2f(hh[(size_t)m*256 + h*64 + o]);
            }
        }
        float Z  = zp + (float)NNODES * base;
        float hp = (acc + base * S[h*64 + o]) / Z;
        hout[(size_t)n*256 + h*64 + o] = fmaxf(hp, 0.f);
    }
}

// ---------------- host: size-based input resolution ----------------
static int find_size(const int* sz, int n, int want, int fallback)
{
    for (int i = 0; i < n; ++i) if (sz[i] == want) return i;
    return fallback;
}

extern "C" void kernel_launch(void* const* d_in, const int* in_sizes, int n_in,
                              void* d_out, int out_size, void* d_ws, size_t ws_size,
                              hipStream_t stream)
{
    int ix   = find_size(in_sizes, n_in, NNODES*D_IN, 0);
    int ie   = find_size(in_sizes, n_in, 2*NEDGES, 1);
    int iwin = find_size(in_sizes, n_in, D_IN*D_H, 2);
    int ibin = find_size(in_sizes, n_in, D_H, 3);
    int iwg  = find_size(in_sizes, n_in, 2*NHEAD*D_H*D_HEAD, 4);
    int ia   = find_size(in_sizes, n_in, 2*NHEAD*2*D_HEAD, 5);
    int iwo  = find_size(in_sizes, n_in, D_H*D_OUT, 6);
    int ibo  = find_size(in_sizes, n_in, D_OUT, 7);

    const float* x    = (const float*)d_in[ix];
    const int*   ei   = (const int*)d_in[ie];
    const float* Win  = (const float*)d_in[iwin];
    const float* bin_ = (const float*)d_in[ibin];
    const float* Wg   = (const float*)d_in[iwg];
    const float* a    = (const float*)d_in[ia];
    const float* Wout = (const float*)d_in[iwo];
    const float* bout = (const float*)d_in[ibo];
    float* out = (float*)d_out;

    char* ws = (char*)d_ws;
    float*          h0    = (float*)(ws + OFF_H0);
    float*          h1    = (float*)(ws + OFF_H1);
    unsigned short* hh    = (unsigned short*)(ws + OFF_HH);
    float*          Spart = (float*)(ws + OFF_SPART);
    float*          ssrc  = (float*)(ws + OFF_SSRC);
    float*          sdst  = (float*)(ws + OFF_SDST);
    float*          S     = (float*)(ws + OFF_S);
    unsigned short* WinT  = (unsigned short*)(ws + OFF_WINT);
    unsigned short* WgT   = (unsigned short*)(ws + OFF_WGT);
    unsigned short* WoutT = (unsigned short*)(ws + OFF_WOUTT);
    unsigned*       bm    = (unsigned*)(ws + OFF_BM);

    // d1: zero bitmap + weight convert (fused, disjoint memory)
    k_init<<<512, 256, 0, stream>>>(Win, Wg, Wout, WinT, WgT, WoutT, (uint4*)bm);
    // d2: adjacency bitmap build
    edge_bitmap<<<NEDGES/256, 256, 0, stream>>>(ei, bm);

    // d3: h0 = relu(x @ Win + bin)
    {
        dim3 g(D_H/64, NNODES/32);
        gemm_mfma<<<g, 256, 0, stream>>>(x, WinT, bin_, h0, nullptr,
                                         NNODES, D_H, D_IN, 1,
                                         nullptr, nullptr, nullptr, nullptr);
    }

    float* hin = h0;
    float* hcur = h1;
    for (int l = 0; l < 2; ++l) {
        // d4/d7: hh = hin @ Wg[l] (bf16 out, + fused scores & column partial sums)
        dim3 g2(D_H/64, NNODES/32);
        gemm_mfma<<<g2, 256, 0, stream>>>(hin, WgT + (size_t)l*NHEAD*D_HEAD*D_H,
                                          nullptr, nullptr, hh,
                                          NNODES, D_H, D_H, 0,
                                          a + (size_t)l*NHEAD*128, ssrc, sdst, Spart);
        // d5/d8: S = colsum(Spart)
        colsum2<<<1, 256, 0, stream>>>(Spart, S);
        // d6/d9: aggregate
        aggregate_kernel<<<NNODES, 256, 0, stream>>>(bm, ssrc, sdst, hh, S, hcur);
        float* t = hin; hin = hcur; hcur = t;
    }

    // d10: out = hin @ Wout + bout
    {
        dim3 g(D_OUT/64, NNODES/32);
        gemm_mfma<<<g, 256, 0, stream>>>(hin, WoutT, bout, out, nullptr,
                                         NNODES, D_OUT, D_H, 0,
                                         nullptr, nullptr, nullptr, nullptr);
    }
}

// Round 14
// 85.236 us; speedup vs baseline: 1.8476x; 1.0184x over previous
//
#include <hip/hip_runtime.h>
#include <hip/hip_bf16.h>

#define NNODES 4096
#define NEDGES 131072
#define D_IN   768
#define D_H    256
#define NHEAD  4
#define D_HEAD 64
#define D_OUT  128
#define DEGCAP 192

typedef __attribute__((ext_vector_type(4))) float f32x4;
typedef __attribute__((ext_vector_type(8))) short bf16x8;
typedef __attribute__((ext_vector_type(8))) unsigned short u16x8;

static __device__ __forceinline__ unsigned short f2bf(float f) {
    __hip_bfloat16 h = __float2bfloat16(f);
    return *reinterpret_cast<unsigned short*>(&h);
}
static __device__ __forceinline__ float bf2f(unsigned short u) {
    return __uint_as_float((unsigned)u << 16);
}

// ---------------- workspace layout (bytes) ----------------
#define OFF_XB     (0u)                          // 4096*768*2 = 6MB (x as bf16)
#define OFF_H0     (6u<<20)                      // 2MB bf16
#define OFF_H1     (8u<<20)                      // 2MB bf16
#define OFF_HH     (10u<<20)                     // 2MB bf16
#define OFF_SPART  (12u<<20)                     // 128*256*4 = 131072
#define OFF_SSRC   (OFF_SPART + 131072u)         // 65536
#define OFF_SDST   (OFF_SSRC + 65536u)           // 65536
#define OFF_S      (OFF_SDST + 65536u)           // 1024
#define OFF_WINT   (OFF_S + 1024u)               // 393216
#define OFF_WGT    (OFF_WINT + 393216u)          // 262144
#define OFF_WOUTT  (OFF_WGT + 262144u)           // 65536
#define OFF_BM     (OFF_WOUTT + 65536u)          // 2MB

// ---------------- init: zero bitmap + weight convert + x -> bf16 ----------------
// 512 blocks. Weight tiles: Win 24x8=192 (bid 0..191), Wg 8x16 (192..319),
// Wout 8x4 (320..351). All blocks also convert x (786432 float4 -> ushort4).
__global__ __launch_bounds__(256) void k_init(
    const float* __restrict__ Win, const float* __restrict__ Wg,
    const float* __restrict__ Wout, const float* __restrict__ x,
    unsigned short* __restrict__ WinT, unsigned short* __restrict__ WgT,
    unsigned short* __restrict__ WoutT, unsigned short* __restrict__ xb,
    uint4* __restrict__ bm4)
{
    __shared__ float tile[32][33];
    const int tid = threadIdx.x, bid = blockIdx.x;
    bm4[bid*256 + tid] = make_uint4(0u,0u,0u,0u);

    // x -> bf16 (identical rounding to the old in-staging convert)
    {
        const float4* x4 = (const float4*)x;
        ushort4* xb4 = (ushort4*)xb;
        for (int i = bid*256 + tid; i < (NNODES*D_IN)/4; i += 512*256) {
            float4 v = x4[i];
            ushort4 o;
            o.x = f2bf(v.x); o.y = f2bf(v.y); o.z = f2bf(v.z); o.w = f2bf(v.w);
            xb4[i] = o;
        }
    }

    if (bid < 352) {
        const float* src; unsigned short* dst; int R, Cc, tr, tc;
        if (bid < 192)      { src = Win;  dst = WinT;  R = 768; Cc = 256; tr = bid >> 3; tc = bid & 7; }
        else if (bid < 320) { int t = bid - 192; int m = t >> 4, s = t & 15;
                              src = Wg + (size_t)m*16384; dst = WgT + (size_t)m*16384;
                              R = 256; Cc = 64; tr = s >> 1; tc = s & 1; }
        else                { int t = bid - 320; src = Wout; dst = WoutT;
                              R = 256; Cc = 128; tr = t >> 2; tc = t & 3; }
        int ci = tid & 31, rq = tid >> 5;
        #pragma unroll
        for (int rr = rq; rr < 32; rr += 8)
            tile[rr][ci] = src[(size_t)(tr*32+rr)*Cc + tc*32 + ci];
        __syncthreads();
        int ri = tid & 31, cq = tid >> 5;
        #pragma unroll
        for (int cc = cq; cc < 32; cc += 8)
            dst[(size_t)(tc*32+cc)*R + tr*32 + ri] = f2bf(tile[ri][cc]);
    }
}

// ---------------- adjacency bitmap (fused dtype autodetect; idempotent) ----------------
__global__ void edge_bitmap(const int* __restrict__ ei, unsigned* __restrict__ bm)
{
    __shared__ int is64_sh;
    int tid = threadIdx.x;
    if (tid < 64) {
        int v = ei[2*tid + 1];
        unsigned long long ball = __ballot(v == 0);
        if (tid == 0) is64_sh = (ball == ~0ull) ? 1 : 0;
    }
    __syncthreads();
    int is64 = is64_sh;
    int k = blockIdx.x*256 + tid;
    if (k >= NEDGES) return;
    int r = is64 ? ei[2*k]            : ei[k];
    int c = is64 ? ei[2*NEDGES + 2*k] : ei[NEDGES + k];
    r &= (NNODES-1); c &= (NNODES-1);
    atomicOr(&bm[(size_t)r*128 + (c>>5)], 1u << (c & 31));
}

// ---------------- MFMA GEMM: C = act(A@B + bias), A/B both bf16 ----------------
// A: MxK bf16 row-major. BT: NxK bf16 (pre-transposed). 32x64 tile, BK=64,
// 256 thr = 4 waves (wave = 16-col strip), 4 MFMA/wave/iter. Staging is pure
// u16x8 copies (no conversion VALU). a_l != null (hh GEMM): epilogue computes
// ssrc/sdst + Spart col sums. Output: Cb (bf16) if non-null else Cf (f32).
__global__ __launch_bounds__(256) void gemm_mfma(
    const unsigned short* __restrict__ A, const unsigned short* __restrict__ BT,
    const float* __restrict__ bias, float* __restrict__ Cf,
    unsigned short* __restrict__ Cb,
    int N, int K, int relu,
    const float* __restrict__ a_l, float* __restrict__ ssrc,
    float* __restrict__ sdst, float* __restrict__ Spart)
{
    __shared__ unsigned short As[32][72];   // [row][k] bf16, 144B stride (2-way banks: free)
    __shared__ unsigned short Bs[64][72];   // [col][k] bf16
    __shared__ float sredS[4][32], sredD[4][32];
    const int tid = threadIdx.x;
    const int bx = blockIdx.x, by = blockIdx.y;
    const int wc = tid >> 6;                 // wave id = column strip
    const int lane = tid & 63;
    const int g = lane >> 4, c = lane & 15;
    const int ar = tid >> 3, ak = (tid & 7) * 8;   // A stage: 32r x (8thr x 8 u16)
    const int bc = tid >> 2, bk = (tid & 3) * 16;  // B stage: 64c x (4thr x 16 u16)
    f32x4 acc0 = {0.f,0.f,0.f,0.f}, acc1 = {0.f,0.f,0.f,0.f};
    const unsigned short* Arow = A + (size_t)(by*32 + ar)*K;
    const unsigned short* Brow = BT + (size_t)(bx*64 + bc)*K;

    for (int k0 = 0; k0 < K; k0 += 64) {
        u16x8 avv = *(const u16x8*)&Arow[k0 + ak];
        u16x8 bv0 = *(const u16x8*)&Brow[k0 + bk];
        u16x8 bv1 = *(const u16x8*)&Brow[k0 + bk + 8];
        *(u16x8*)&As[ar][ak]     = avv;
        *(u16x8*)&Bs[bc][bk]     = bv0;
        *(u16x8*)&Bs[bc][bk + 8] = bv1;
        __syncthreads();
        bf16x8 b0  = *(bf16x8*)&Bs[wc*16 + c][g*8];
        bf16x8 b1  = *(bf16x8*)&Bs[wc*16 + c][32 + g*8];
        bf16x8 a00 = *(bf16x8*)&As[c][g*8];
        bf16x8 a01 = *(bf16x8*)&As[c][32 + g*8];
        bf16x8 a10 = *(bf16x8*)&As[16 + c][g*8];
        bf16x8 a11 = *(bf16x8*)&As[16 + c][32 + g*8];
        acc0 = __builtin_amdgcn_mfma_f32_16x16x32_bf16(a00, b0, acc0, 0, 0, 0);
        acc0 = __builtin_amdgcn_mfma_f32_16x16x32_bf16(a01, b1, acc0, 0, 0, 0);
        acc1 = __builtin_amdgcn_mfma_f32_16x16x32_bf16(a10, b0, acc1, 0, 0, 0);
        acc1 = __builtin_amdgcn_mfma_f32_16x16x32_bf16(a11, b1, acc1, 0, 0, 0);
        __syncthreads();
    }

    const int col = bx*64 + wc*16 + c;
    float bb = bias ? bias[col] : 0.f;
    #pragma unroll
    for (int t = 0; t < 2; ++t) {
        f32x4 av = t ? acc1 : acc0;
        #pragma unroll
        for (int i = 0; i < 4; ++i) {
            int r = by*32 + t*16 + g*4 + i;
            float v = av[i] + bb;
            if (relu) v = fmaxf(v, 0.f);
            if (Cb) Cb[(size_t)r*N + col] = f2bf(v);
            else    Cf[(size_t)r*N + col] = v;
        }
    }

    if (a_l) {
        int h = bx;
        float as = a_l[h*128 + wc*16 + c];
        float ad = a_l[h*128 + 64 + wc*16 + c];
        float ps[8], pd[8], cs = 0.f;
        #pragma unroll
        for (int t = 0; t < 2; ++t) {
            f32x4 av = t ? acc1 : acc0;
            #pragma unroll
            for (int i = 0; i < 4; ++i) {
                ps[t*4+i] = av[i] * as;
                pd[t*4+i] = av[i] * ad;
                cs += av[i];
            }
        }
        #pragma unroll
        for (int off = 1; off < 16; off <<= 1) {
            #pragma unroll
            for (int j = 0; j < 8; ++j) {
                ps[j] += __shfl_xor(ps[j], off);
                pd[j] += __shfl_xor(pd[j], off);
            }
        }
        if (c == 0) {
            #pragma unroll
            for (int t = 0; t < 2; ++t)
                #pragma unroll
                for (int i = 0; i < 4; ++i) {
                    sredS[wc][t*16 + g*4 + i] = ps[t*4+i];
                    sredD[wc][t*16 + g*4 + i] = pd[t*4+i];
                }
        }
        cs += __shfl_xor(cs, 16);
        cs += __shfl_xor(cs, 32);
        if (g == 0)
            Spart[by*256 + h*64 + wc*16 + c] = cs;
        __syncthreads();
        if (tid < 32) {
            float s1 = sredS[0][tid] + sredS[1][tid] + sredS[2][tid] + sredS[3][tid];
            float s2 = sredD[0][tid] + sredD[1][tid] + sredD[2][tid] + sredD[3][tid];
            int r = by*32 + tid;
            ssrc[r*4 + h] = s1;
            sdst[r*4 + h] = s2;
        }
    }
}

// ---------------- colsum stage 2: S[c] = sum_by Spart[by][c] ----------------
__global__ void colsum2(const float* __restrict__ Spart, float* __restrict__ S)
{
    int j = threadIdx.x;
    float s = 0.f;
    for (int b = 0; b < 128; ++b) s += Spart[b*256 + j];
    S[j] = s;                     // deterministic
}

// ---------------- per-node aggregation + dense-softmax + relu (bf16 out) ----------------
// Neighbor list built in-kernel from the bitmap row. Exact dense-softmax identity:
//   M = max(0, max_e e); base = exp(-M)
//   Z = sum_edges(exp(e-M)-base) + N*base
//   hp = [ sum_edges (exp(e-M)-base)*hh[m] + base*S ] / Z
__global__ __launch_bounds__(256) void aggregate_kernel(
    const unsigned* __restrict__ bm,
    const float* __restrict__ ssrc, const float* __restrict__ sdst,
    const unsigned short* __restrict__ hh, const float* __restrict__ S,
    unsigned short* __restrict__ hout)
{
    __shared__ int   csr_lds[DEGCAP];
    __shared__ float w_lds[4*DEGCAP];
    __shared__ int   cnt_sh;
    int n = blockIdx.x;
    int tid = threadIdx.x;
    int h = tid >> 6, o = tid & 63;
    const unsigned* brow = bm + (size_t)n*128;

    if (tid < 64) {
        unsigned wA = brow[2*tid], wB = brow[2*tid + 1];
        int cpc = __popc(wA) + __popc(wB);
        int pre = cpc;
        #pragma unroll
        for (int off = 1; off < 64; off <<= 1) {
            int v = __shfl_up(pre, off);
            if (tid >= off) pre += v;
        }
        int excl = pre - cpc;
        int total = __shfl(pre, 63);
        if (total <= DEGCAP) {
            int pos = excl, base = tid*64;
            unsigned w = wA;
            while (w) { int b = __builtin_ctz(w); csr_lds[pos++] = base + b; w &= w-1; }
            w = wB; base += 32;
            while (w) { int b = __builtin_ctz(w); csr_lds[pos++] = base + b; w &= w-1; }
        }
        if (tid == 0) cnt_sh = total;
    }
    __syncthreads();
    int cnt = cnt_sh;
    float ss = ssrc[n*4 + h];

    if (cnt <= DEGCAP) {
        float mx = 0.f;
        for (int i = o; i < cnt; i += 64) {
            int m = csr_lds[i];
            float e = ss + sdst[m*4 + h];
            e = (e >= 0.f) ? e : 0.2f*e;
            mx = fmaxf(mx, e);
        }
        #pragma unroll
        for (int off = 32; off; off >>= 1) mx = fmaxf(mx, __shfl_xor(mx, off));
        float M = mx;
        float base = expf(-M);

        float zp = 0.f;
        for (int i = o; i < cnt; i += 64) {
            int m = csr_lds[i];
            float e = ss + sdst[m*4 + h];
            e = (e >= 0.f) ? e : 0.2f*e;
            float w = expf(e - M) - base;
            w_lds[h*DEGCAP + i] = w;
            zp += w;
        }
        #pragma unroll
        for (int off = 32; off; off >>= 1) zp += __shfl_xor(zp, off);

        // accumulate: 8 independent gathers in flight (same sequential FP order)
        float acc = 0.f;
        int i = 0;
        for (; i + 8 <= cnt; i += 8) {
            int   mm[8]; float wq[8]; float vq[8];
            #pragma unroll
            for (int j = 0; j < 8; ++j) {
                mm[j] = csr_lds[i+j];
                wq[j] = w_lds[h*DEGCAP + i + j];
            }
            #pragma unroll
            for (int j = 0; j < 8; ++j)
                vq[j] = bf2f(hh[(size_t)mm[j]*256 + h*64 + o]);
            #pragma unroll
            for (int j = 0; j < 8; ++j)
                acc += wq[j] * vq[j];
        }
        for (; i < cnt; ++i)
            acc += w_lds[h*DEGCAP+i] * bf2f(hh[(size_t)csr_lds[i]*256 + h*64 + o]);

        float Z  = zp + (float)NNODES * base;
        float hp = (acc + base * S[h*64 + o]) / Z;
        hout[(size_t)n*256 + h*64 + o] = f2bf(fmaxf(hp, 0.f));
    } else {
        float mx = 0.f;
        for (int m = o; m < NNODES; m += 64) {
            if ((brow[m>>5] >> (m & 31)) & 1u) {
                float e = ss + sdst[m*4 + h];
                e = (e >= 0.f) ? e : 0.2f*e;
                mx = fmaxf(mx, e);
            }
        }
        #pragma unroll
        for (int off = 32; off; off >>= 1) mx = fmaxf(mx, __shfl_xor(mx, off));
        float M = mx;
        float base = expf(-M);
        float zp = 0.f, acc = 0.f;
        for (int m = 0; m < NNODES; ++m) {
            if ((brow[m>>5] >> (m & 31)) & 1u) {
                float e = ss + sdst[m*4 + h];
                e = (e >= 0.f) ? e : 0.2f*e;
                float w = expf(e - M) - base;
                zp += w;
                acc += w * bf2f(hh[(size_t)m*256 + h*64 + o]);
            }
        }
        float Z  = zp + (float)NNODES * base;
        float hp = (acc + base * S[h*64 + o]) / Z;
        hout[(size_t)n*256 + h*64 + o] = f2bf(fmaxf(hp, 0.f));
    }
}

// ---------------- host: size-based input resolution ----------------
static int find_size(const int* sz, int n, int want, int fallback)
{
    for (int i = 0; i < n; ++i) if (sz[i] == want) return i;
    return fallback;
}

extern "C" void kernel_launch(void* const* d_in, const int* in_sizes, int n_in,
                              void* d_out, int out_size, void* d_ws, size_t ws_size,
                              hipStream_t stream)
{
    int ix   = find_size(in_sizes, n_in, NNODES*D_IN, 0);
    int ie   = find_size(in_sizes, n_in, 2*NEDGES, 1);
    int iwin = find_size(in_sizes, n_in, D_IN*D_H, 2);
    int ibin = find_size(in_sizes, n_in, D_H, 3);
    int iwg  = find_size(in_sizes, n_in, 2*NHEAD*D_H*D_HEAD, 4);
    int ia   = find_size(in_sizes, n_in, 2*NHEAD*2*D_HEAD, 5);
    int iwo  = find_size(in_sizes, n_in, D_H*D_OUT, 6);
    int ibo  = find_size(in_sizes, n_in, D_OUT, 7);

    const float* x    = (const float*)d_in[ix];
    const int*   ei   = (const int*)d_in[ie];
    const float* Win  = (const float*)d_in[iwin];
    const float* bin_ = (const float*)d_in[ibin];
    const float* Wg   = (const float*)d_in[iwg];
    const float* a    = (const float*)d_in[ia];
    const float* Wout = (const float*)d_in[iwo];
    const float* bout = (const float*)d_in[ibo];
    float* out = (float*)d_out;

    char* ws = (char*)d_ws;
    unsigned short* xb    = (unsigned short*)(ws + OFF_XB);
    unsigned short* h0    = (unsigned short*)(ws + OFF_H0);
    unsigned short* h1    = (unsigned short*)(ws + OFF_H1);
    unsigned short* hh    = (unsigned short*)(ws + OFF_HH);
    float*          Spart = (float*)(ws + OFF_SPART);
    float*          ssrc  = (float*)(ws + OFF_SSRC);
    float*          sdst  = (float*)(ws + OFF_SDST);
    float*          S     = (float*)(ws + OFF_S);
    unsigned short* WinT  = (unsigned short*)(ws + OFF_WINT);
    unsigned short* WgT   = (unsigned short*)(ws + OFF_WGT);
    unsigned short* WoutT = (unsigned short*)(ws + OFF_WOUTT);
    unsigned*       bm    = (unsigned*)(ws + OFF_BM);

    // d1: zero bitmap + weight convert + x->bf16 (disjoint memory)
    k_init<<<512, 256, 0, stream>>>(Win, Wg, Wout, x, WinT, WgT, WoutT, xb, (uint4*)bm);
    // d2: adjacency bitmap build
    edge_bitmap<<<NEDGES/256, 256, 0, stream>>>(ei, bm);

    // d3: h0 = relu(xb @ Win + bin)  (bf16 out)
    {
        dim3 g(D_H/64, NNODES/32);
        gemm_mfma<<<g, 256, 0, stream>>>(xb, WinT, bin_, nullptr, h0,
                                         D_H, D_IN, 1,
                                         nullptr, nullptr, nullptr, nullptr);
    }

    unsigned short* hin = h0;
    unsigned short* hcur = h1;
    for (int l = 0; l < 2; ++l) {
        // d4/d7: hh = hin @ Wg[l] (bf16 out, + fused scores & column partial sums)
        dim3 g2(D_H/64, NNODES/32);
        gemm_mfma<<<g2, 256, 0, stream>>>(hin, WgT + (size_t)l*NHEAD*D_HEAD*D_H,
                                          nullptr, nullptr, hh,
                                          D_H, D_H, 0,
                                          a + (size_t)l*NHEAD*128, ssrc, sdst, Spart);
        // d5/d8: S = colsum(Spart)
        colsum2<<<1, 256, 0, stream>>>(Spart, S);
        // d6/d9: aggregate (bf16 out)
        aggregate_kernel<<<NNODES, 256, 0, stream>>>(bm, ssrc, sdst, hh, S, hcur);
        unsigned short* t = hin; hin = hcur; hcur = t;
    }

    // d10: out = hin @ Wout + bout  (f32 out)
    {
        dim3 g(D_OUT/64, NNODES/32);
        gemm_mfma<<<g, 256, 0, stream>>>(hin, WoutT, bout, out, nullptr,
                                         D_OUT, D_H, 0,
                                         nullptr, nullptr, nullptr, nullptr);
    }
}

// Round 15
// 79.655 us; speedup vs baseline: 1.9771x; 1.0701x over previous
//
#include <hip/hip_runtime.h>
#include <hip/hip_bf16.h>

#define NNODES 4096
#define NEDGES 131072
#define D_IN   768
#define D_H    256
#define NHEAD  4
#define D_HEAD 64
#define D_OUT  128
#define DEGCAP 192
#define S_SCALE 1048576.0f          // 2^20 fixed-point for deterministic S atomics

typedef __attribute__((ext_vector_type(4))) float f32x4;
typedef __attribute__((ext_vector_type(8))) short bf16x8;
typedef __attribute__((ext_vector_type(8))) unsigned short u16x8;

static __device__ __forceinline__ unsigned short f2bf(float f) {
    __hip_bfloat16 h = __float2bfloat16(f);
    return *reinterpret_cast<unsigned short*>(&h);
}
static __device__ __forceinline__ float bf2f(unsigned short u) {
    return __uint_as_float((unsigned)u << 16);
}

// ---------------- workspace layout (bytes) ----------------
#define OFF_XB     (0u)                          // 4096*768*2 = 6MB (x as bf16)
#define OFF_H0     (6u<<20)                      // 2MB bf16
#define OFF_H1     (8u<<20)                      // 2MB bf16
#define OFF_HH     (10u<<20)                     // 2MB bf16
#define OFF_SINT   (12u<<20)                     // 2 layers * 256 * 8B = 4096
#define OFF_SSRC   (OFF_SINT + 4096u)            // 65536
#define OFF_SDST   (OFF_SSRC + 65536u)           // 65536
#define OFF_WINT   (OFF_SDST + 65536u)           // 393216
#define OFF_WGT    (OFF_WINT + 393216u)          // 262144
#define OFF_WOUTT  (OFF_WGT + 262144u)           // 65536
#define OFF_BM     (OFF_WOUTT + 65536u)          // 2MB

// ---------------- init: zero bitmap + Sint + weight convert + x -> bf16 ----------------
// 512 blocks. Weight tiles: Win 24x8=192 (bid 0..191), Wg 8x16 (192..319),
// Wout 8x4 (320..351). All blocks also convert x (786432 float4 -> ushort4).
__global__ __launch_bounds__(256) void k_init(
    const float* __restrict__ Win, const float* __restrict__ Wg,
    const float* __restrict__ Wout, const float* __restrict__ x,
    unsigned short* __restrict__ WinT, unsigned short* __restrict__ WgT,
    unsigned short* __restrict__ WoutT, unsigned short* __restrict__ xb,
    uint4* __restrict__ bm4, unsigned long long* __restrict__ Sint)
{
    __shared__ float tile[32][33];
    const int tid = threadIdx.x, bid = blockIdx.x;
    bm4[bid*256 + tid] = make_uint4(0u,0u,0u,0u);
    if (bid == 0) { Sint[tid] = 0ull; Sint[256 + tid] = 0ull; }

    // x -> bf16 (identical rounding to in-staging convert)
    {
        const float4* x4 = (const float4*)x;
        ushort4* xb4 = (ushort4*)xb;
        for (int i = bid*256 + tid; i < (NNODES*D_IN)/4; i += 512*256) {
            float4 v = x4[i];
            ushort4 o;
            o.x = f2bf(v.x); o.y = f2bf(v.y); o.z = f2bf(v.z); o.w = f2bf(v.w);
            xb4[i] = o;
        }
    }

    if (bid < 352) {
        const float* src; unsigned short* dst; int R, Cc, tr, tc;
        if (bid < 192)      { src = Win;  dst = WinT;  R = 768; Cc = 256; tr = bid >> 3; tc = bid & 7; }
        else if (bid < 320) { int t = bid - 192; int m = t >> 4, s = t & 15;
                              src = Wg + (size_t)m*16384; dst = WgT + (size_t)m*16384;
                              R = 256; Cc = 64; tr = s >> 1; tc = s & 1; }
        else                { int t = bid - 320; src = Wout; dst = WoutT;
                              R = 256; Cc = 128; tr = t >> 2; tc = t & 3; }
        int ci = tid & 31, rq = tid >> 5;
        #pragma unroll
        for (int rr = rq; rr < 32; rr += 8)
            tile[rr][ci] = src[(size_t)(tr*32+rr)*Cc + tc*32 + ci];
        __syncthreads();
        int ri = tid & 31, cq = tid >> 5;
        #pragma unroll
        for (int cc = cq; cc < 32; cc += 8)
            dst[(size_t)(tc*32+cc)*R + tr*32 + ri] = f2bf(tile[ri][cc]);
    }
}

// ---------------- adjacency bitmap (fused dtype autodetect; idempotent) ----------------
__global__ void edge_bitmap(const int* __restrict__ ei, unsigned* __restrict__ bm)
{
    __shared__ int is64_sh;
    int tid = threadIdx.x;
    if (tid < 64) {
        int v = ei[2*tid + 1];
        unsigned long long ball = __ballot(v == 0);
        if (tid == 0) is64_sh = (ball == ~0ull) ? 1 : 0;
    }
    __syncthreads();
    int is64 = is64_sh;
    int k = blockIdx.x*256 + tid;
    if (k >= NEDGES) return;
    int r = is64 ? ei[2*k]            : ei[k];
    int c = is64 ? ei[2*NEDGES + 2*k] : ei[NEDGES + k];
    r &= (NNODES-1); c &= (NNODES-1);
    atomicOr(&bm[(size_t)r*128 + (c>>5)], 1u << (c & 31));
}

// ---------------- MFMA GEMM: C = act(A@B + bias), A/B both bf16 ----------------
// A: MxK bf16 row-major. BT: NxK bf16 (pre-transposed). 32x64 tile, BK=64,
// 256 thr = 4 waves (wave = 16-col strip), 4 MFMA/wave/iter.
// a_l != null (hh GEMM): epilogue computes ssrc/sdst and adds this block's
// 32-row column sums into Sint[col] via fixed-point int64 atomics
// (exactly associative -> deterministic regardless of block order).
__global__ __launch_bounds__(256) void gemm_mfma(
    const unsigned short* __restrict__ A, const unsigned short* __restrict__ BT,
    const float* __restrict__ bias, float* __restrict__ Cf,
    unsigned short* __restrict__ Cb,
    int N, int K, int relu,
    const float* __restrict__ a_l, float* __restrict__ ssrc,
    float* __restrict__ sdst, unsigned long long* __restrict__ Sint)
{
    __shared__ unsigned short As[32][72];   // [row][k] bf16, 144B stride (2-way banks: free)
    __shared__ unsigned short Bs[64][72];   // [col][k] bf16
    __shared__ float sredS[4][32], sredD[4][32];
    const int tid = threadIdx.x;
    const int bx = blockIdx.x, by = blockIdx.y;
    const int wc = tid >> 6;                 // wave id = column strip
    const int lane = tid & 63;
    const int g = lane >> 4, c = lane & 15;
    const int ar = tid >> 3, ak = (tid & 7) * 8;   // A stage: 32r x (8thr x 8 u16)
    const int bc = tid >> 2, bk = (tid & 3) * 16;  // B stage: 64c x (4thr x 16 u16)
    f32x4 acc0 = {0.f,0.f,0.f,0.f}, acc1 = {0.f,0.f,0.f,0.f};
    const unsigned short* Arow = A + (size_t)(by*32 + ar)*K;
    const unsigned short* Brow = BT + (size_t)(bx*64 + bc)*K;

    for (int k0 = 0; k0 < K; k0 += 64) {
        u16x8 avv = *(const u16x8*)&Arow[k0 + ak];
        u16x8 bv0 = *(const u16x8*)&Brow[k0 + bk];
        u16x8 bv1 = *(const u16x8*)&Brow[k0 + bk + 8];
        *(u16x8*)&As[ar][ak]     = avv;
        *(u16x8*)&Bs[bc][bk]     = bv0;
        *(u16x8*)&Bs[bc][bk + 8] = bv1;
        __syncthreads();
        bf16x8 b0  = *(bf16x8*)&Bs[wc*16 + c][g*8];
        bf16x8 b1  = *(bf16x8*)&Bs[wc*16 + c][32 + g*8];
        bf16x8 a00 = *(bf16x8*)&As[c][g*8];
        bf16x8 a01 = *(bf16x8*)&As[c][32 + g*8];
        bf16x8 a10 = *(bf16x8*)&As[16 + c][g*8];
        bf16x8 a11 = *(bf16x8*)&As[16 + c][32 + g*8];
        acc0 = __builtin_amdgcn_mfma_f32_16x16x32_bf16(a00, b0, acc0, 0, 0, 0);
        acc0 = __builtin_amdgcn_mfma_f32_16x16x32_bf16(a01, b1, acc0, 0, 0, 0);
        acc1 = __builtin_amdgcn_mfma_f32_16x16x32_bf16(a10, b0, acc1, 0, 0, 0);
        acc1 = __builtin_amdgcn_mfma_f32_16x16x32_bf16(a11, b1, acc1, 0, 0, 0);
        __syncthreads();
    }

    const int col = bx*64 + wc*16 + c;
    float bb = bias ? bias[col] : 0.f;
    #pragma unroll
    for (int t = 0; t < 2; ++t) {
        f32x4 av = t ? acc1 : acc0;
        #pragma unroll
        for (int i = 0; i < 4; ++i) {
            int r = by*32 + t*16 + g*4 + i;
            float v = av[i] + bb;
            if (relu) v = fmaxf(v, 0.f);
            if (Cb) Cb[(size_t)r*N + col] = f2bf(v);
            else    Cf[(size_t)r*N + col] = v;
        }
    }

    if (a_l) {
        int h = bx;
        float as = a_l[h*128 + wc*16 + c];
        float ad = a_l[h*128 + 64 + wc*16 + c];
        float ps[8], pd[8], cs = 0.f;
        #pragma unroll
        for (int t = 0; t < 2; ++t) {
            f32x4 av = t ? acc1 : acc0;
            #pragma unroll
            for (int i = 0; i < 4; ++i) {
                ps[t*4+i] = av[i] * as;
                pd[t*4+i] = av[i] * ad;
                cs += av[i];
            }
        }
        #pragma unroll
        for (int off = 1; off < 16; off <<= 1) {
            #pragma unroll
            for (int j = 0; j < 8; ++j) {
                ps[j] += __shfl_xor(ps[j], off);
                pd[j] += __shfl_xor(pd[j], off);
            }
        }
        if (c == 0) {
            #pragma unroll
            for (int t = 0; t < 2; ++t)
                #pragma unroll
                for (int i = 0; i < 4; ++i) {
                    sredS[wc][t*16 + g*4 + i] = ps[t*4+i];
                    sredD[wc][t*16 + g*4 + i] = pd[t*4+i];
                }
        }
        // 32-row column sum -> deterministic fixed-point atomic
        cs += __shfl_xor(cs, 16);
        cs += __shfl_xor(cs, 32);
        if (g == 0) {
            long long q = (long long)llrintf(cs * S_SCALE);
            atomicAdd(&Sint[col], (unsigned long long)q);   // 2's-complement add
        }
        __syncthreads();
        if (tid < 32) {
            float s1 = sredS[0][tid] + sredS[1][tid] + sredS[2][tid] + sredS[3][tid];
            float s2 = sredD[0][tid] + sredD[1][tid] + sredD[2][tid] + sredD[3][tid];
            int r = by*32 + tid;
            ssrc[r*4 + h] = s1;
            sdst[r*4 + h] = s2;
        }
    }
}

// ---------------- per-node aggregation + dense-softmax + relu (bf16 out) ----------------
// Neighbor list built in-kernel from the bitmap row. Exact dense-softmax identity:
//   M = max(0, max_e e); base = exp(-M)
//   Z = sum_edges(exp(e-M)-base) + N*base
//   hp = [ sum_edges (exp(e-M)-base)*hh[m] + base*S ] / Z
__global__ __launch_bounds__(256) void aggregate_kernel(
    const unsigned* __restrict__ bm,
    const float* __restrict__ ssrc, const float* __restrict__ sdst,
    const unsigned short* __restrict__ hh,
    const unsigned long long* __restrict__ Sint,
    unsigned short* __restrict__ hout)
{
    __shared__ int   csr_lds[DEGCAP];
    __shared__ float w_lds[4*DEGCAP];
    __shared__ int   cnt_sh;
    int n = blockIdx.x;
    int tid = threadIdx.x;
    int h = tid >> 6, o = tid & 63;
    const unsigned* brow = bm + (size_t)n*128;
    float Sv = (float)(long long)Sint[h*64 + o] * (1.0f / S_SCALE);

    if (tid < 64) {
        unsigned wA = brow[2*tid], wB = brow[2*tid + 1];
        int cpc = __popc(wA) + __popc(wB);
        int pre = cpc;
        #pragma unroll
        for (int off = 1; off < 64; off <<= 1) {
            int v = __shfl_up(pre, off);
            if (tid >= off) pre += v;
        }
        int excl = pre - cpc;
        int total = __shfl(pre, 63);
        if (total <= DEGCAP) {
            int pos = excl, base = tid*64;
            unsigned w = wA;
            while (w) { int b = __builtin_ctz(w); csr_lds[pos++] = base + b; w &= w-1; }
            w = wB; base += 32;
            while (w) { int b = __builtin_ctz(w); csr_lds[pos++] = base + b; w &= w-1; }
        }
        if (tid == 0) cnt_sh = total;
    }
    __syncthreads();
    int cnt = cnt_sh;
    float ss = ssrc[n*4 + h];

    if (cnt <= DEGCAP) {
        float mx = 0.f;
        for (int i = o; i < cnt; i += 64) {
            int m = csr_lds[i];
            float e = ss + sdst[m*4 + h];
            e = (e >= 0.f) ? e : 0.2f*e;
            mx = fmaxf(mx, e);
        }
        #pragma unroll
        for (int off = 32; off; off >>= 1) mx = fmaxf(mx, __shfl_xor(mx, off));
        float M = mx;
        float base = expf(-M);

        float zp = 0.f;
        for (int i = o; i < cnt; i += 64) {
            int m = csr_lds[i];
            float e = ss + sdst[m*4 + h];
            e = (e >= 0.f) ? e : 0.2f*e;
            float w = expf(e - M) - base;
            w_lds[h*DEGCAP + i] = w;
            zp += w;
        }
        #pragma unroll
        for (int off = 32; off; off >>= 1) zp += __shfl_xor(zp, off);

        // accumulate: 8 independent gathers in flight (same sequential FP order)
        float acc = 0.f;
        int i = 0;
        for (; i + 8 <= cnt; i += 8) {
            int   mm[8]; float wq[8]; float vq[8];
            #pragma unroll
            for (int j = 0; j < 8; ++j) {
                mm[j] = csr_lds[i+j];
                wq[j] = w_lds[h*DEGCAP + i + j];
            }
            #pragma unroll
            for (int j = 0; j < 8; ++j)
                vq[j] = bf2f(hh[(size_t)mm[j]*256 + h*64 + o]);
            #pragma unroll
            for (int j = 0; j < 8; ++j)
                acc += wq[j] * vq[j];
        }
        for (; i < cnt; ++i)
            acc += w_lds[h*DEGCAP+i] * bf2f(hh[(size_t)csr_lds[i]*256 + h*64 + o]);

        float Z  = zp + (float)NNODES * base;
        float hp = (acc + base * Sv) / Z;
        hout[(size_t)n*256 + h*64 + o] = f2bf(fmaxf(hp, 0.f));
    } else {
        float mx = 0.f;
        for (int m = o; m < NNODES; m += 64) {
            if ((brow[m>>5] >> (m & 31)) & 1u) {
                float e = ss + sdst[m*4 + h];
                e = (e >= 0.f) ? e : 0.2f*e;
                mx = fmaxf(mx, e);
            }
        }
        #pragma unroll
        for (int off = 32; off; off >>= 1) mx = fmaxf(mx, __shfl_xor(mx, off));
        float M = mx;
        float base = expf(-M);
        float zp = 0.f, acc = 0.f;
        for (int m = 0; m < NNODES; ++m) {
            if ((brow[m>>5] >> (m & 31)) & 1u) {
                float e = ss + sdst[m*4 + h];
                e = (e >= 0.f) ? e : 0.2f*e;
                float w = expf(e - M) - base;
                zp += w;
                acc += w * bf2f(hh[(size_t)m*256 + h*64 + o]);
            }
        }
        float Z  = zp + (float)NNODES * base;
        float hp = (acc + base * Sv) / Z;
        hout[(size_t)n*256 + h*64 + o] = f2bf(fmaxf(hp, 0.f));
    }
}

// ---------------- host: size-based input resolution ----------------
static int find_size(const int* sz, int n, int want, int fallback)
{
    for (int i = 0; i < n; ++i) if (sz[i] == want) return i;
    return fallback;
}

extern "C" void kernel_launch(void* const* d_in, const int* in_sizes, int n_in,
                              void* d_out, int out_size, void* d_ws, size_t ws_size,
                              hipStream_t stream)
{
    int ix   = find_size(in_sizes, n_in, NNODES*D_IN, 0);
    int ie   = find_size(in_sizes, n_in, 2*NEDGES, 1);
    int iwin = find_size(in_sizes, n_in, D_IN*D_H, 2);
    int ibin = find_size(in_sizes, n_in, D_H, 3);
    int iwg  = find_size(in_sizes, n_in, 2*NHEAD*D_H*D_HEAD, 4);
    int ia   = find_size(in_sizes, n_in, 2*NHEAD*2*D_HEAD, 5);
    int iwo  = find_size(in_sizes, n_in, D_H*D_OUT, 6);
    int ibo  = find_size(in_sizes, n_in, D_OUT, 7);

    const float* x    = (const float*)d_in[ix];
    const int*   ei   = (const int*)d_in[ie];
    const float* Win  = (const float*)d_in[iwin];
    const float* bin_ = (const float*)d_in[ibin];
    const float* Wg   = (const float*)d_in[iwg];
    const float* a    = (const float*)d_in[ia];
    const float* Wout = (const float*)d_in[iwo];
    const float* bout = (const float*)d_in[ibo];
    float* out = (float*)d_out;

    char* ws = (char*)d_ws;
    unsigned short*     xb    = (unsigned short*)(ws + OFF_XB);
    unsigned short*     h0    = (unsigned short*)(ws + OFF_H0);
    unsigned short*     h1    = (unsigned short*)(ws + OFF_H1);
    unsigned short*     hh    = (unsigned short*)(ws + OFF_HH);
    unsigned long long* Sint  = (unsigned long long*)(ws + OFF_SINT);
    float*              ssrc  = (float*)(ws + OFF_SSRC);
    float*              sdst  = (float*)(ws + OFF_SDST);
    unsigned short*     WinT  = (unsigned short*)(ws + OFF_WINT);
    unsigned short*     WgT   = (unsigned short*)(ws + OFF_WGT);
    unsigned short*     WoutT = (unsigned short*)(ws + OFF_WOUTT);
    unsigned*           bm    = (unsigned*)(ws + OFF_BM);

    // d1: zero bitmap + Sint + weight convert + x->bf16 (disjoint memory)
    k_init<<<512, 256, 0, stream>>>(Win, Wg, Wout, x, WinT, WgT, WoutT, xb,
                                    (uint4*)bm, Sint);
    // d2: adjacency bitmap build
    edge_bitmap<<<NEDGES/256, 256, 0, stream>>>(ei, bm);

    // d3: h0 = relu(xb @ Win + bin)  (bf16 out)
    {
        dim3 g(D_H/64, NNODES/32);
        gemm_mfma<<<g, 256, 0, stream>>>(xb, WinT, bin_, nullptr, h0,
                                         D_H, D_IN, 1,
                                         nullptr, nullptr, nullptr, nullptr);
    }

    unsigned short* hin = h0;
    unsigned short* hcur = h1;
    for (int l = 0; l < 2; ++l) {
        // d4/d6: hh = hin @ Wg[l] (bf16 out, + scores + fixed-point S atomics)
        dim3 g2(D_H/64, NNODES/32);
        gemm_mfma<<<g2, 256, 0, stream>>>(hin, WgT + (size_t)l*NHEAD*D_HEAD*D_H,
                                          nullptr, nullptr, hh,
                                          D_H, D_H, 0,
                                          a + (size_t)l*NHEAD*128, ssrc, sdst,
                                          Sint + (size_t)l*256);
        // d5/d7: aggregate (bf16 out)
        aggregate_kernel<<<NNODES, 256, 0, stream>>>(bm, ssrc, sdst, hh,
                                                     Sint + (size_t)l*256, hcur);
        unsigned short* t = hin; hin = hcur; hcur = t;
    }

    // d8: out = hin @ Wout + bout  (f32 out)
    {
        dim3 g(D_OUT/64, NNODES/32);
        gemm_mfma<<<g, 256, 0, stream>>>(hin, WoutT, bout, out, nullptr,
                                         D_OUT, D_H, 0,
                                         nullptr, nullptr, nullptr, nullptr);
    }
}